// Round 2
// baseline (365.590 us; speedup 1.0000x reference)
//
#include <hip/hip_runtime.h>
#include <stdint.h>

// Problem constants (fixed by the reference)
#define CHARS   10000
#define KPAD    10240   // K padded to multiple of 64
#define HIDDEN  1024
#define OUTPUT  100
#define OPAD    128     // padded output cols for coalesced W2T
#define BATCH   4096
#define MAXLEN  2048

typedef __bf16 bf16_t;
typedef __bf16 bf16x8 __attribute__((ext_vector_type(8)));
typedef float  f32x4  __attribute__((ext_vector_type(4)));

// ---------------------------------------------------------------------------
// async global->LDS 16B copy (m97 pattern: wave-uniform base + lane*16)
// ---------------------------------------------------------------------------
__device__ inline void gload_lds16(const void* g, void* l) {
    __builtin_amdgcn_global_load_lds(
        (const __attribute__((address_space(1))) uint32_t*)g,
        (__attribute__((address_space(3))) uint32_t*)l,
        16, 0, 0);
}

// ---------------------------------------------------------------------------
// W1 (HIDDEN x CHARS fp32) -> W1b (HIDDEN x KPAD bf16), zero-padded cols.
// ---------------------------------------------------------------------------
__global__ void k_w1bf16(const float* __restrict__ W1, bf16_t* __restrict__ W1b) {
    int c = blockIdx.x * 256 + threadIdx.x;   // 0..KPAD-1
    int h = blockIdx.y;                       // 0..HIDDEN-1
    float v = (c < CHARS) ? W1[(size_t)h * CHARS + c] : 0.0f;
    W1b[(size_t)h * KPAD + c] = (bf16_t)v;
}

// ---------------------------------------------------------------------------
// W2 (OUTPUT x HIDDEN fp32) -> W2T (HIDDEN x OPAD fp32), zero-padded cols.
// ---------------------------------------------------------------------------
__global__ void k_w2t(const float* __restrict__ W2, float* __restrict__ W2T) {
    int o = threadIdx.x;      // 0..127
    int k = blockIdx.x;       // 0..1023
    W2T[(size_t)k * OPAD + o] = (o < OUTPUT) ? W2[(size_t)o * HIDDEN + k] : 0.0f;
}

// ---------------------------------------------------------------------------
// hid pre-init with b1 (split-K GEMM atomically accumulates on top)
// ---------------------------------------------------------------------------
__global__ void k_hidinit(const float* __restrict__ b1, float* __restrict__ hid) {
    int h = blockIdx.y * 256 + threadIdx.x;   // 0..1023
    hid[(size_t)blockIdx.x * HIDDEN + h] = b1[h];
}

// ---------------------------------------------------------------------------
// Per-row histogram: one block per batch row. 40KB LDS uint32 counts.
// Counts are tiny integers -> exact in bf16.
// ---------------------------------------------------------------------------
__global__ void k_hist(const int* __restrict__ words, bf16_t* __restrict__ hist,
                       int rowStart) {
    __shared__ uint32_t h[KPAD];              // 40 KB
    const int tid = threadIdx.x;
    for (int i = tid; i < KPAD; i += 256) h[i] = 0u;
    __syncthreads();
    const int* w = words + (size_t)(rowStart + blockIdx.x) * MAXLEN;
    for (int i = tid; i < MAXLEN; i += 256)
        atomicAdd(&h[w[i]], 1u);
    __syncthreads();
    bf16_t* dst = hist + (size_t)blockIdx.x * KPAD;
    for (int i = tid; i < KPAD; i += 256)
        dst[i] = (bf16_t)(float)h[i];
}

// ---------------------------------------------------------------------------
// bf16 MFMA GEMM (m97 structure + XOR-swizzled LDS):
//   C[m,n] += A[m,k] * Bt[n,k]
//   128x128 tile, BK=64, 16x16x32 MFMA, global_load_lds width=16 staging.
//   LDS chunk c of row r holds global 16B-chunk (c ^ (r&7)) -> conflict-free
//   ds_read_b128 (8 lanes per bank-quad, the wave64 floor).
//   Split-K over blockIdx.z -> fp32 atomicAdd into pre-initialized hid.
// ---------------------------------------------------------------------------
__global__ void __launch_bounds__(256)
k_gemm(const bf16_t* __restrict__ A, const bf16_t* __restrict__ Bt,
       float* __restrict__ hid, int ksteps_per_slice) {
    __shared__ __attribute__((aligned(16))) bf16_t As[128 * 64];
    __shared__ __attribute__((aligned(16))) bf16_t Bs[128 * 64];

    const int tid  = threadIdx.x;
    const int lane = tid & 63;
    const int wave = tid >> 6;
    const int m0 = blockIdx.x * 128;
    const int n0 = blockIdx.y * 128;
    const int kbeg = blockIdx.z * ksteps_per_slice * 64;
    const int kend = kbeg + ksteps_per_slice * 64;

    // staging: issue i covers rows i*32 + (tid>>3); LDS dest forced to
    // base + tid*16. Source chunk is XOR-swizzled by row so that
    // LDS(r, c) = global chunk c ^ (r&7).
    const int srow = tid >> 3;                       // 0..31
    const int gch  = (tid & 7) ^ (srow & 7);         // swizzled source chunk
    const bf16_t* Ag = A  + (size_t)(m0 + srow) * KPAD + gch * 8;
    const bf16_t* Bg = Bt + (size_t)(n0 + srow) * KPAD + gch * 8;

    f32x4 acc[4][4] = {};
    const int wm = (wave & 1) * 64;       // wave's 64x64 sub-tile
    const int wn = (wave >> 1) * 64;
    const int fr = lane & 15;             // m/n index within 16
    const int qd = lane >> 4;             // quad -> k-octet index

    for (int k0 = kbeg; k0 < kend; k0 += 64) {
#pragma unroll
        for (int i = 0; i < 4; ++i) {
            gload_lds16(Ag + (size_t)i * 32 * KPAD + k0, As + i * 2048 + tid * 8);
            gload_lds16(Bg + (size_t)i * 32 * KPAD + k0, Bs + i * 2048 + tid * 8);
        }
        __syncthreads();
#pragma unroll
        for (int kk = 0; kk < 64; kk += 32) {
            const int gc = (kk >> 3) + qd;           // global chunk 0..7
            bf16x8 af[4], bfr[4];
#pragma unroll
            for (int i = 0; i < 4; ++i) {
                const int R = wm + i * 16 + fr;
                af[i] = *(const bf16x8*)(As + R * 64 + ((gc ^ (R & 7)) * 8));
            }
#pragma unroll
            for (int j = 0; j < 4; ++j) {
                const int R = wn + j * 16 + fr;
                bfr[j] = *(const bf16x8*)(Bs + R * 64 + ((gc ^ (R & 7)) * 8));
            }
#pragma unroll
            for (int i = 0; i < 4; ++i)
#pragma unroll
                for (int j = 0; j < 4; ++j)
                    acc[i][j] = __builtin_amdgcn_mfma_f32_16x16x32_bf16(
                        af[i], bfr[j], acc[i][j], 0, 0, 0);
        }
        __syncthreads();
    }

    // epilogue: C/D layout col=lane&15, row=(lane>>4)*4+reg  [guide §3, m89]
    const int er = (lane >> 4) * 4;
    const int ec = lane & 15;
#pragma unroll
    for (int i = 0; i < 4; ++i) {
#pragma unroll
        for (int j = 0; j < 4; ++j) {
            float* dst = hid + (size_t)(m0 + wm + i * 16 + er) * HIDDEN
                             + (n0 + wn + j * 16 + ec);
#pragma unroll
            for (int r = 0; r < 4; ++r)
                atomicAdd(dst + (size_t)r * HIDDEN, acc[i][j][r]);
        }
    }
}

// ---------------------------------------------------------------------------
// out[b,o] = sum_k hid[b,k] * W2T[k,o] + b2[o]
// ---------------------------------------------------------------------------
__global__ void k_out(const float* __restrict__ hid, const float* __restrict__ W2T,
                      const float* __restrict__ b2, float* __restrict__ out) {
    const int tid = threadIdx.x;
    const int o4  = (tid & 31) * 4;       // 0,4,...,124
    const int rs  = tid >> 5;             // 0..7
    const int row = blockIdx.x * 8 + rs;
    const float* hrow = hid + (size_t)row * HIDDEN;
    f32x4 acc = {0.f, 0.f, 0.f, 0.f};
    for (int k0 = 0; k0 < HIDDEN; k0 += 4) {
        f32x4 hv = *(const f32x4*)(hrow + k0);
#pragma unroll
        for (int q = 0; q < 4; ++q) {
            f32x4 wv = *(const f32x4*)(W2T + (size_t)(k0 + q) * OPAD + o4);
            acc += hv[q] * wv;
        }
    }
    if (o4 < OUTPUT) {
        float* op = out + (size_t)row * OUTPUT + o4;
#pragma unroll
        for (int q = 0; q < 4; ++q)
            op[q] = acc[q] + b2[o4 + q];
    }
}

// ---------------------------------------------------------------------------
static inline int pick_split(int mtiles) {
    // want ~1280 blocks total (5 blocks/CU, the 32KB-LDS cap);
    // S must divide 160 k-steps
    int target = 1280 / (mtiles * 8);
    if (target < 1) target = 1;
    const int divs[12] = {160, 80, 40, 32, 20, 16, 10, 8, 5, 4, 2, 1};
    for (int i = 0; i < 12; ++i)
        if (divs[i] <= target) return divs[i];
    return 1;
}

extern "C" void kernel_launch(void* const* d_in, const int* in_sizes, int n_in,
                              void* d_out, int out_size, void* d_ws, size_t ws_size,
                              hipStream_t stream) {
    (void)in_sizes; (void)n_in; (void)out_size;
    const int*   words = (const int*)d_in[0];
    const float* W1    = (const float*)d_in[1];
    const float* b1    = (const float*)d_in[2];
    const float* W2    = (const float*)d_in[3];
    const float* b2    = (const float*)d_in[4];
    float* out = (float*)d_out;

    // workspace layout
    char* ws = (char*)d_ws;
    size_t off = 0;
    bf16_t* W1b  = (bf16_t*)(ws + off); off += (size_t)HIDDEN * KPAD * sizeof(bf16_t); // 21.0 MB
    float*  hid  = (float*) (ws + off); off += (size_t)BATCH * HIDDEN * sizeof(float); // 16.8 MB
    float*  W2T  = (float*) (ws + off); off += (size_t)HIDDEN * OPAD * sizeof(float);  // 0.5 MB
    bf16_t* histC = (bf16_t*)(ws + off);
    size_t rem = (ws_size > off) ? (ws_size - off) : 0;
    int chunkRows = (int)(rem / ((size_t)KPAD * sizeof(bf16_t)));
    chunkRows = (chunkRows / 128) * 128;
    if (chunkRows > BATCH) chunkRows = BATCH;
    if (chunkRows < 128)   chunkRows = 128;

    k_w1bf16<<<dim3(KPAD / 256, HIDDEN), dim3(256), 0, stream>>>(W1, W1b);
    k_w2t<<<dim3(HIDDEN), dim3(OPAD), 0, stream>>>(W2, W2T);
    k_hidinit<<<dim3(BATCH, HIDDEN / 256), dim3(256), 0, stream>>>(b1, hid);

    for (int r0 = 0; r0 < BATCH; r0 += chunkRows) {
        int rows = BATCH - r0;
        if (rows > chunkRows) rows = chunkRows;
        k_hist<<<dim3(rows), dim3(256), 0, stream>>>(words, histC, r0);
        int mtiles = rows / 128;
        int S = pick_split(mtiles);
        int ksteps = (KPAD / 64) / S;
        k_gemm<<<dim3(mtiles, HIDDEN / 128, S), dim3(256), 0, stream>>>(
            histC, W1b, hid + (size_t)r0 * HIDDEN, ksteps);
    }

    k_out<<<dim3(BATCH / 8), dim3(256), 0, stream>>>(hid, W2T, b2, out);
}

// Round 3
// 351.258 us; speedup vs baseline: 1.0408x; 1.0408x over previous
//
#include <hip/hip_runtime.h>
#include <stdint.h>

// Problem constants (fixed by the reference)
#define CHARS   10000
#define KPAD    10240   // K padded to multiple of 64
#define HIDDEN  1024
#define OUTPUT  100
#define OPAD    128     // padded output cols for coalesced W2T
#define BATCH   4096
#define MAXLEN  2048
#define LDST    72      // LDS row stride in bf16 (64 data + 8 pad) = 144 B

typedef __bf16 bf16_t;
typedef __bf16 bf16x8 __attribute__((ext_vector_type(8)));
typedef float  f32x4  __attribute__((ext_vector_type(4)));

// ---------------------------------------------------------------------------
// W1 (HIDDEN x CHARS fp32) -> W1b (HIDDEN x KPAD bf16), zero-padded cols.
// ---------------------------------------------------------------------------
__global__ void k_w1bf16(const float* __restrict__ W1, bf16_t* __restrict__ W1b) {
    int c = blockIdx.x * 256 + threadIdx.x;   // 0..KPAD-1
    int h = blockIdx.y;                       // 0..HIDDEN-1
    float v = (c < CHARS) ? W1[(size_t)h * CHARS + c] : 0.0f;
    W1b[(size_t)h * KPAD + c] = (bf16_t)v;
}

// ---------------------------------------------------------------------------
// W2 (OUTPUT x HIDDEN fp32) -> W2T (HIDDEN x OPAD fp32), zero-padded cols.
// ---------------------------------------------------------------------------
__global__ void k_w2t(const float* __restrict__ W2, float* __restrict__ W2T) {
    int o = threadIdx.x;      // 0..127
    int k = blockIdx.x;       // 0..1023
    W2T[(size_t)k * OPAD + o] = (o < OUTPUT) ? W2[(size_t)o * HIDDEN + k] : 0.0f;
}

// ---------------------------------------------------------------------------
// hid pre-init with b1 (split-K GEMM atomically accumulates on top)
// ---------------------------------------------------------------------------
__global__ void k_hidinit(const float* __restrict__ b1, float* __restrict__ hid) {
    int h = blockIdx.y * 256 + threadIdx.x;   // 0..1023
    hid[(size_t)blockIdx.x * HIDDEN + h] = b1[h];
}

// ---------------------------------------------------------------------------
// Per-row histogram: one block per batch row. 40KB LDS uint32 counts.
// Counts are tiny integers -> exact in bf16.
// ---------------------------------------------------------------------------
__global__ void k_hist(const int* __restrict__ words, bf16_t* __restrict__ hist,
                       int rowStart) {
    __shared__ uint32_t h[KPAD];              // 40 KB
    const int tid = threadIdx.x;
    for (int i = tid; i < KPAD; i += 256) h[i] = 0u;
    __syncthreads();
    const int* w = words + (size_t)(rowStart + blockIdx.x) * MAXLEN;
    for (int i = tid; i < MAXLEN; i += 256)
        atomicAdd(&h[w[i]], 1u);
    __syncthreads();
    bf16_t* dst = hist + (size_t)blockIdx.x * KPAD;
    for (int i = tid; i < KPAD; i += 256)
        dst[i] = (bf16_t)(float)h[i];
}

// ---------------------------------------------------------------------------
// bf16 MFMA GEMM, software-pipelined via VGPR staging:
//   C[m,n] += A[m,k] * Bt[n,k]
//   128x128 tile, BK=64, 16x16x32 MFMA.
//   Pipeline: [ds_write regs(k)] barrier [issue global loads k+1 -> regs]
//             [compute k from LDS] barrier -> next iter.
//   The vmcnt(0) drain at the trailing barrier overlaps the whole compute
//   phase, hiding L3/HBM latency that the global_load_lds version exposed.
//   LDS rows padded to 72 bf16 (144B): ds_read_b128/ds_write_b128 both land
//   at the optimal 8 dwords/bank (verified by bank arithmetic).
//   Split-K over blockIdx.z -> fp32 atomicAdd into pre-initialized hid.
// ---------------------------------------------------------------------------
__global__ void __launch_bounds__(256)
k_gemm(const bf16_t* __restrict__ A, const bf16_t* __restrict__ Bt,
       float* __restrict__ hid, int ksteps_per_slice) {
    __shared__ __attribute__((aligned(16))) bf16_t As[128 * LDST];  // 18 KB
    __shared__ __attribute__((aligned(16))) bf16_t Bs[128 * LDST];  // 18 KB

    const int tid  = threadIdx.x;
    const int lane = tid & 63;
    const int wave = tid >> 6;
    const int m0 = blockIdx.x * 128;
    const int n0 = blockIdx.y * 128;
    const int kbeg = blockIdx.z * ksteps_per_slice * 64;
    const int kend = kbeg + ksteps_per_slice * 64;

    // staging map: thread covers rows srow + 32*i (i=0..3), 16B chunk (tid&7)
    const int srow = tid >> 3;            // 0..31
    const int scol = (tid & 7) * 8;
    const bf16_t* Ag = A  + (size_t)(m0 + srow) * KPAD + scol;
    const bf16_t* Bg = Bt + (size_t)(n0 + srow) * KPAD + scol;
    bf16_t* Awr = As + srow * LDST + scol;
    bf16_t* Bwr = Bs + srow * LDST + scol;

    f32x4 acc[4][4] = {};
    const int wm = (wave & 1) * 64;       // wave's 64x64 sub-tile
    const int wn = (wave >> 1) * 64;
    const int fr = lane & 15;             // m/n index within 16
    const int fk = (lane >> 4) * 8;       // k-octet

    // prologue: load first k-step into registers
    bf16x8 rA[4], rB[4];
#pragma unroll
    for (int i = 0; i < 4; ++i) {
        rA[i] = *(const bf16x8*)(Ag + (size_t)i * 32 * KPAD + kbeg);
        rB[i] = *(const bf16x8*)(Bg + (size_t)i * 32 * KPAD + kbeg);
    }

    for (int k0 = kbeg; k0 < kend; k0 += 64) {
        // commit regs (step k0) to LDS
#pragma unroll
        for (int i = 0; i < 4; ++i) {
            *(bf16x8*)(Awr + i * 32 * LDST) = rA[i];
            *(bf16x8*)(Bwr + i * 32 * LDST) = rB[i];
        }
        __syncthreads();
        // prefetch step k0+64 (lands during compute; drained at 2nd barrier)
        if (k0 + 64 < kend) {
#pragma unroll
            for (int i = 0; i < 4; ++i) {
                rA[i] = *(const bf16x8*)(Ag + (size_t)i * 32 * KPAD + k0 + 64);
                rB[i] = *(const bf16x8*)(Bg + (size_t)i * 32 * KPAD + k0 + 64);
            }
        }
        // compute step k0 from LDS
#pragma unroll
        for (int kk = 0; kk < 64; kk += 32) {
            bf16x8 af[4], bfr[4];
#pragma unroll
            for (int i = 0; i < 4; ++i)
                af[i] = *(const bf16x8*)(As + (wm + i * 16 + fr) * LDST + kk + fk);
#pragma unroll
            for (int j = 0; j < 4; ++j)
                bfr[j] = *(const bf16x8*)(Bs + (wn + j * 16 + fr) * LDST + kk + fk);
#pragma unroll
            for (int i = 0; i < 4; ++i)
#pragma unroll
                for (int j = 0; j < 4; ++j)
                    acc[i][j] = __builtin_amdgcn_mfma_f32_16x16x32_bf16(
                        af[i], bfr[j], acc[i][j], 0, 0, 0);
        }
        __syncthreads();
    }

    // epilogue: C/D layout col=lane&15, row=(lane>>4)*4+reg  [guide §3, m89]
    const int er = (lane >> 4) * 4;
    const int ec = lane & 15;
#pragma unroll
    for (int i = 0; i < 4; ++i) {
#pragma unroll
        for (int j = 0; j < 4; ++j) {
            float* dst = hid + (size_t)(m0 + wm + i * 16 + er) * HIDDEN
                             + (n0 + wn + j * 16 + ec);
#pragma unroll
            for (int r = 0; r < 4; ++r)
                atomicAdd(dst + (size_t)r * HIDDEN, acc[i][j][r]);
        }
    }
}

// ---------------------------------------------------------------------------
// out[b,o] = sum_k hid[b,k] * W2T[k,o] + b2[o]
// ---------------------------------------------------------------------------
__global__ void k_out(const float* __restrict__ hid, const float* __restrict__ W2T,
                      const float* __restrict__ b2, float* __restrict__ out) {
    const int tid = threadIdx.x;
    const int o4  = (tid & 31) * 4;       // 0,4,...,124
    const int rs  = tid >> 5;             // 0..7
    const int row = blockIdx.x * 8 + rs;
    const float* hrow = hid + (size_t)row * HIDDEN;
    f32x4 acc = {0.f, 0.f, 0.f, 0.f};
    for (int k0 = 0; k0 < HIDDEN; k0 += 4) {
        f32x4 hv = *(const f32x4*)(hrow + k0);
#pragma unroll
        for (int q = 0; q < 4; ++q) {
            f32x4 wv = *(const f32x4*)(W2T + (size_t)(k0 + q) * OPAD + o4);
            acc += hv[q] * wv;
        }
    }
    if (o4 < OUTPUT) {
        float* op = out + (size_t)row * OUTPUT + o4;
#pragma unroll
        for (int q = 0; q < 4; ++q)
            op[q] = acc[q] + b2[o4 + q];
    }
}

// ---------------------------------------------------------------------------
static inline int pick_split(int mtiles) {
    // target 512 blocks = one full residency round at 2 blocks/CU;
    // S must divide 160 k-steps
    int target = 512 / (mtiles * 8);
    if (target < 1) target = 1;
    const int divs[12] = {160, 80, 40, 32, 20, 16, 10, 8, 5, 4, 2, 1};
    for (int i = 0; i < 12; ++i)
        if (divs[i] <= target) return divs[i];
    return 1;
}

extern "C" void kernel_launch(void* const* d_in, const int* in_sizes, int n_in,
                              void* d_out, int out_size, void* d_ws, size_t ws_size,
                              hipStream_t stream) {
    (void)in_sizes; (void)n_in; (void)out_size;
    const int*   words = (const int*)d_in[0];
    const float* W1    = (const float*)d_in[1];
    const float* b1    = (const float*)d_in[2];
    const float* W2    = (const float*)d_in[3];
    const float* b2    = (const float*)d_in[4];
    float* out = (float*)d_out;

    // workspace layout
    char* ws = (char*)d_ws;
    size_t off = 0;
    bf16_t* W1b  = (bf16_t*)(ws + off); off += (size_t)HIDDEN * KPAD * sizeof(bf16_t); // 21.0 MB
    float*  hid  = (float*) (ws + off); off += (size_t)BATCH * HIDDEN * sizeof(float); // 16.8 MB
    float*  W2T  = (float*) (ws + off); off += (size_t)HIDDEN * OPAD * sizeof(float);  // 0.5 MB
    bf16_t* histC = (bf16_t*)(ws + off);
    size_t rem = (ws_size > off) ? (ws_size - off) : 0;
    int chunkRows = (int)(rem / ((size_t)KPAD * sizeof(bf16_t)));
    chunkRows = (chunkRows / 128) * 128;
    if (chunkRows > BATCH) chunkRows = BATCH;
    if (chunkRows < 128)   chunkRows = 128;

    k_w1bf16<<<dim3(KPAD / 256, HIDDEN), dim3(256), 0, stream>>>(W1, W1b);
    k_w2t<<<dim3(HIDDEN), dim3(OPAD), 0, stream>>>(W2, W2T);
    k_hidinit<<<dim3(BATCH, HIDDEN / 256), dim3(256), 0, stream>>>(b1, hid);

    for (int r0 = 0; r0 < BATCH; r0 += chunkRows) {
        int rows = BATCH - r0;
        if (rows > chunkRows) rows = chunkRows;
        k_hist<<<dim3(rows), dim3(256), 0, stream>>>(words, histC, r0);
        int mtiles = rows / 128;
        int S = pick_split(mtiles);
        int ksteps = (KPAD / 64) / S;
        k_gemm<<<dim3(mtiles, HIDDEN / 128, S), dim3(256), 0, stream>>>(
            histC, W1b, hid + (size_t)r0 * HIDDEN, ksteps);
    }

    k_out<<<dim3(BATCH / 8), dim3(256), 0, stream>>>(hid, W2T, b2, out);
}